// Round 6
// baseline (19.689 us; speedup 1.0000x reference)
//
#include <hip/hip_runtime.h>
#include <math.h>

#define N_ 2
#define C_ 32
#define X_ 48
#define Y_ 48
#define Z_ 24
#define M_ (X_*Y_*Z_)   // 55296
#define NM_ (N_*M_)     // 110592

#define TX_ 2
#define TY_ 4
#define HX_ (TX_+2)          // 4
#define HY_ (TY_+2)          // 6
#define HVOX_ (HX_*HY_*Z_)   // 576 halo voxels
#define TVOX_ (TX_*TY_*Z_)   // 192 output voxels
#define THREADS_ 384         // 2 threads per output voxel (channel halves)
#define NXT_ (X_/TX_)        // 24
#define NYT_ (Y_/TY_)        // 12

typedef _Float16 h2 __attribute__((ext_vector_type(2)));

#if __has_builtin(__builtin_amdgcn_fdot2)
__device__ __forceinline__ float dot2(h2 a, h2 b, float c) {
    return __builtin_amdgcn_fdot2(a, b, c, false);
}
#else
__device__ __forceinline__ float dot2(h2 a, h2 b, float c) {
    return fmaf((float)a[1], (float)b[1], fmaf((float)a[0], (float)b[0], c));
}
#endif

// Single fused kernel, both HBM streams in flight together:
//  Phase 0: ISSUE own-voxel f0 loads (16 ch) into registers -- the waitcnt
//           lands after the barrier, so f0 latency hides under phase 1.
//  Phase 1: load raw f1 halo, L2-normalize, store fp16 voxel-major in LDS
//           (XOR-swizzled 16B quads).
//  Phase 2: f0 norm (cross-half shfl), 27 neighbor dots from LDS, online
//           no-max softmax (logits bounded by exp(logit_scale)=14.29).
__global__ __launch_bounds__(THREADS_) void fused_kernel(
    const float* __restrict__ f0, const float* __restrict__ f1,
    const float* __restrict__ logit_scale, float* __restrict__ out)
{
    __shared__ int4 lds[HVOX_ * 4];   // 36,864 B

    const int tid = threadIdx.x;
    const int bid = blockIdx.x;
    const int n   = bid / (NXT_ * NYT_);
    const int rem = bid - n * (NXT_ * NYT_);
    const int xt  = rem % NXT_;
    const int yt  = rem / NXT_;
    const int x0  = xt * TX_;
    const int y0  = yt * TY_;

    // ---------------- Phase 0: issue f0 loads early ------------------------
    const int lane = tid & 63;
    const int w    = tid >> 6;
    const int hi   = lane >> 5;          // channel half
    const int slot = lane & 31;
    const int ov   = w * 32 + slot;      // 0..191, tz-consecutive
    const int tz   = ov % Z_;
    const int txy  = ov / Z_;
    const int ty   = txy % TY_;
    const int tx   = txy / TY_;
    const int gx = x0 + tx, gy = y0 + ty, gz = tz;
    const int gm = (gx * Y_ + gy) * Z_ + gz;

    const float* p0 = f0 + (size_t)n * C_ * M_ + (size_t)hi * 16 * M_ + gm;
    float a[16];
#pragma unroll
    for (int i = 0; i < 16; ++i) a[i] = p0[(size_t)i * M_];
    float lsv = logit_scale[0];

    // ---------------- Phase 1: f1 halo -> normalized fp16 in LDS ----------
    const float* f1b = f1 + (size_t)n * C_ * M_;
    for (int h = tid; h < HVOX_; h += THREADS_) {
        int hx = h / (HY_ * Z_);
        int rh = h - hx * (HY_ * Z_);
        int hy = rh / Z_;
        int hz = rh - hy * Z_;
        int ggx = min(max(x0 - 1 + hx, 0), X_ - 1);
        int ggy = min(max(y0 - 1 + hy, 0), Y_ - 1);
        int ggm = (ggx * Y_ + ggy) * Z_ + hz;

        float b[C_];
        float s = 0.f;
#pragma unroll
        for (int c = 0; c < C_; ++c) {
            b[c] = f1b[(size_t)c * M_ + ggm];
            s = fmaf(b[c], b[c], s);
        }
        float rs = 1.0f / (sqrtf(s) + 1e-7f);
#pragma unroll
        for (int q = 0; q < 4; ++q) {            // quad q holds channels 8q..8q+7
            union { int4 qq; h2 hh[4]; } u;
#pragma unroll
            for (int e = 0; e < 4; ++e) {
                h2 v2;
                v2[0] = (_Float16)(b[8 * q + 2 * e]     * rs);
                v2[1] = (_Float16)(b[8 * q + 2 * e + 1] * rs);
                u.hh[e] = v2;
            }
            lds[h * 4 + (q ^ ((h >> 1) & 3))] = u.qq;   // bank swizzle
        }
    }
    __syncthreads();

    // ---------------- Phase 2: per-voxel dots + softmax --------------------
    float s0 = 0.f;
#pragma unroll
    for (int i = 0; i < 16; ++i) s0 = fmaf(a[i], a[i], s0);
    s0 += __shfl_xor(s0, 32, 64);
    float rs0 = __expf(lsv) / (sqrtf(s0) + 1e-7f);
    h2 A[8];
#pragma unroll
    for (int i = 0; i < 8; ++i) {
        h2 v;
        v[0] = (_Float16)(a[2 * i]     * rs0);
        v[1] = (_Float16)(a[2 * i + 1] * rs0);
        A[i] = v;
    }

    float S = 0.f, FX = 0.f, FY = 0.f, FZ = 0.f;
#pragma unroll
    for (int i = 0; i < 3; ++i)
#pragma unroll
    for (int j = 0; j < 3; ++j)
#pragma unroll
    for (int k = 0; k < 3; ++k) {
        bool val = (gx + i - 1 >= 0) & (gx + i - 1 < X_) &
                   (gy + j - 1 >= 0) & (gy + j - 1 < Y_) &
                   (gz + k - 1 >= 0) & (gz + k - 1 < Z_);
        int hz = min(max(tz + k - 1, 0), Z_ - 1);
        int v  = (tx + i) * (HY_ * Z_) + (ty + j) * Z_ + hz;
        union { int4 qq; h2 hh[4]; } B0, B1;
        int vx = (v >> 1) & 3;
        B0.qq = lds[v * 4 + ((2 * hi)     ^ vx)];
        B1.qq = lds[v * 4 + ((2 * hi + 1) ^ vx)];
        float d = 0.f;
#pragma unroll
        for (int e = 0; e < 4; ++e) d = dot2(A[e],     B0.hh[e], d);
#pragma unroll
        for (int e = 0; e < 4; ++e) d = dot2(A[4 + e], B1.hh[e], d);
        d += __shfl_xor(d, 32, 64);          // full 32-channel dot
        d = val ? d : 0.0f;                  // invalid -> logit exactly 0
        float e_ = __expf(d);                // bounded: |logit| <= 14.29
        S += e_;
        if (i == 0) FX -= e_; else if (i == 2) FX += e_;
        if (j == 0) FY -= e_; else if (j == 2) FY += e_;
        if (k == 0) FZ -= e_; else if (k == 2) FZ += e_;
    }

    if (hi == 0) {
        float inv = 1.0f / S;
        size_t ob = ((size_t)n * M_ + gm) * 3;
        out[ob + 0] = FX * inv;
        out[ob + 1] = FY * inv;
        out[ob + 2] = FZ * inv;
    }
}

extern "C" void kernel_launch(void* const* d_in, const int* in_sizes, int n_in,
                              void* d_out, int out_size, void* d_ws, size_t ws_size,
                              hipStream_t stream) {
    const float* f0 = (const float*)d_in[0];
    const float* f1 = (const float*)d_in[1];
    const float* ls = (const float*)d_in[3];
    float* out = (float*)d_out;

    const int blocks = NXT_ * NYT_ * N_;     // 576
    fused_kernel<<<blocks, THREADS_, 0, stream>>>(f0, f1, ls, out);
}